// Round 1
// baseline (429.286 us; speedup 1.0000x reference)
//
#include <hip/hip_runtime.h>
#include <math.h>

// -------------------------------------------------------------------------
// UpperBandEntropyLoss16: 16x16 block DCT -> zigzag upper band (128 coeffs)
// -> adaptive threshold -> L2 normalize -> mean entropy (scalar out).
//
// Layout: one 256-thread workgroup handles a 16-row x 256-col strip
// (= 16 DCT blocks). Grid = 24 (b*c) * 64 (block rows) * 4 (col groups)
// = 6144 workgroups. DCT basis is baked into constexpr immediates (no LDS
// traffic for H). Entropy reductions are wave-level shuffles; one atomicAdd
// per wave into d_out (memset to 0 at launch).
// -------------------------------------------------------------------------

__constant__ int kZZ[128] = {
    135, 150, 165, 180, 195, 210, 225, 240, 241, 226, 211, 196, 181, 166,
    151, 136, 121, 106, 91,  76,  61,  46,  31,  47,  62,  77,  92,  107,
    122, 137, 152, 167, 182, 197, 212, 227, 242, 243, 228, 213, 198, 183,
    168, 153, 138, 123, 108, 93,  78,  63,  79,  94,  109, 124, 139, 154,
    169, 184, 199, 214, 229, 244, 245, 230, 215, 200, 185, 170, 155, 140,
    125, 110, 95,  111, 126, 141, 156, 171, 186, 201, 216, 231, 246, 247,
    232, 217, 202, 187, 172, 157, 142, 127, 143, 158, 173, 188, 203, 218,
    233, 248, 249, 234, 219, 204, 189, 174, 159, 175, 190, 205, 220, 235,
    250, 251, 236, 221, 206, 191, 207, 222, 237, 252, 253, 238, 223, 239,
    254, 255};

constexpr double kPi = 3.14159265358979323846;

// constexpr cosine (double): range-reduce then Taylor. Accurate to ~1e-15,
// applied to the float32-rounded argument to match numpy's f32 HARM build.
constexpr double ccos(double x) {
    while (x > kPi) x -= 2.0 * kPi;
    while (x < -kPi) x += 2.0 * kPi;
    double x2 = x * x;
    double term = 1.0, sum = 1.0;
    for (int k = 1; k <= 24; ++k) {
        term *= -x2 / (double)((2 * k - 1) * (2 * k));
        sum += term;
    }
    return sum;
}

struct DctTables {
    // Both tables indexed [spatial][freq]; normalization applied on freq idx.
    float g1[16][16];  // H[j][v] * n_v              (stage 1, row DCT)
    float g2[16][16];  // H[i][u] * n_u * SCALE      (stage 2, col DCT)
    constexpr DctTables() : g1{}, g2{} {
        for (int j = 0; j < 16; ++j) {
            for (int f = 0; f < 16; ++f) {
                // numpy: colf = f32(f32(f*pi) / 32); arg = f32((2j+1) * colf)
                float colf = (float)((double)f * kPi) / 32.0f;
                float arg = (2.0f * (float)j + 1.0f) * colf;
                float h = (float)ccos((double)arg);
                float n = (f == 0) ? 0.70710678118654752440f : 1.0f;
                g1[j][f] = h * n;
                g2[j][f] = h * n * 0.17677669529663688110f;  // 1/sqrt(32)
            }
        }
    }
};
constexpr DctTables kT;

#define XS_PITCH 260  // 256 + 4 pad (keeps 16B align; breaks pow2 strides)
#define CS_PITCH 272  // 272 % 32 == 16 -> coeff writes are exact 2-way (free)

__global__ __launch_bounds__(256, 4) void dct_entropy_kernel(
    const float* __restrict__ x, float* __restrict__ out) {
    __shared__ float bufA[16 * CS_PITCH];  // Xs (pitch 260), later Cs (pitch 272)
    __shared__ float Ts[16 * XS_PITCH];

    const int t = threadIdx.x;
    const int g = blockIdx.x;
    const int bc = g >> 8;         // 0..23  (b*c)
    const int br = (g >> 2) & 63;  // block row
    const int cg = g & 3;          // 256-col group
    const float* base =
        x + ((size_t)bc << 20) + ((size_t)br << 14) + ((size_t)cg << 8);

    // ---- global -> LDS: 16 rows x 256 floats, float4, fully coalesced ----
#pragma unroll
    for (int k = 0; k < 4; ++k) {
        int idx = t + 256 * k;  // float4 index within strip
        int row = idx >> 6;
        int c4 = idx & 63;
        float4 ld = *(const float4*)(base + (size_t)row * 1024 + c4 * 4);
        *(float4*)(&bufA[row * XS_PITCH + c4 * 4]) = ld;
    }
    __syncthreads();

    // ---- stage 1: row DCT. thread = (block b, row i) ----
    {
        const int b = t >> 4;
        const int i = t & 15;
        float xr[16];
        const float* src = &bufA[i * XS_PITCH + b * 16];
#pragma unroll
        for (int c = 0; c < 4; ++c) {
            float4 ld = *(const float4*)(src + 4 * c);
            xr[4 * c + 0] = ld.x;
            xr[4 * c + 1] = ld.y;
            xr[4 * c + 2] = ld.z;
            xr[4 * c + 3] = ld.w;
        }
#pragma unroll
        for (int v = 0; v < 16; ++v) {
            float acc = 0.0f;
#pragma unroll
            for (int j = 0; j < 16; ++j) acc = fmaf(xr[j], kT.g1[j][v], acc);
            Ts[v * XS_PITCH + b * 16 + i] = acc;  // transposed write
        }
    }
    __syncthreads();

    // ---- stage 2: col DCT + scale. thread = (block b, col v) ----
    {
        const int b = t >> 4;
        const int v = t & 15;
        float ti[16];
        const float* src = &Ts[v * XS_PITCH + b * 16];
#pragma unroll
        for (int c = 0; c < 4; ++c) {
            float4 ld = *(const float4*)(src + 4 * c);
            ti[4 * c + 0] = ld.x;
            ti[4 * c + 1] = ld.y;
            ti[4 * c + 2] = ld.z;
            ti[4 * c + 3] = ld.w;
        }
#pragma unroll
        for (int u = 0; u < 16; ++u) {
            float acc = 0.0f;
#pragma unroll
            for (int i = 0; i < 16; ++i) acc = fmaf(ti[i], kT.g2[i][u], acc);
            bufA[b * CS_PITCH + u * 16 + v] = acc;  // scaled coeff, flat u*16+v
        }
    }
    __syncthreads();

    // ---- entropy: wave w handles blocks 4w..4w+3, 2 zigzag coeffs/lane ----
    {
        const int lane = t & 63;
        const int w = t >> 6;
        const int z0 = kZZ[2 * lane];
        const int z1 = kZZ[2 * lane + 1];
        float esum = 0.0f;
#pragma unroll
        for (int q = 0; q < 4; ++q) {
            const float* C = &bufA[(4 * w + q) * CS_PITCH];
            float c0 = C[z0];
            float c1 = C[z1];
            // per-block mean of the 128 gathered coeffs
            float s = c0 + c1;
#pragma unroll
            for (int off = 32; off > 0; off >>= 1) s += __shfl_down(s, off);
            float mean = __shfl(s, 0) * (1.0f / 128.0f);
            // threshold -> abs + eps
            float a0 = (c0 < mean) ? 1e-12f : (fabsf(c0) + 1e-12f);
            float a1 = (c1 < mean) ? 1e-12f : (fabsf(c1) + 1e-12f);
            // L2 norm
            float sq = fmaf(a0, a0, a1 * a1);
#pragma unroll
            for (int off = 32; off > 0; off >>= 1) sq += __shfl_down(sq, off);
            float norm = fmaxf(sqrtf(__shfl(sq, 0)), 1e-12f);
            float inv = 1.0f / norm;
            // -sum p log2 p  (accumulate +sum p log2 p, negate at the end)
            float p0 = a0 * inv;
            float p1 = a1 * inv;
            float e = fmaf(p0, __log2f(p0), p1 * __log2f(p1));
#pragma unroll
            for (int off = 32; off > 0; off >>= 1) e += __shfl_down(e, off);
            if (lane == 0) esum += e;
        }
        if (lane == 0) atomicAdd(out, esum * (-1.0f / 98304.0f));
    }
}

extern "C" void kernel_launch(void* const* d_in, const int* in_sizes, int n_in,
                              void* d_out, int out_size, void* d_ws,
                              size_t ws_size, hipStream_t stream) {
    const float* x = (const float*)d_in[0];
    float* out = (float*)d_out;
    // d_out is re-poisoned to 0xAA before every replay; zero it on-stream.
    hipMemsetAsync(out, 0, sizeof(float), stream);
    dct_entropy_kernel<<<6144, 256, 0, stream>>>(x, out);
}

// Round 2
// 147.424 us; speedup vs baseline: 2.9119x; 2.9119x over previous
//
#include <hip/hip_runtime.h>
#include <math.h>

// -------------------------------------------------------------------------
// UpperBandEntropyLoss16: 16x16 block DCT -> upper zigzag band (128 coeffs)
// -> adaptive threshold -> L2 normalize -> mean entropy (scalar out).
//
// R1 -> R2: removed the 24576 same-address atomicAdds (WRITE_SIZE showed
// 768 KB = 24576 x 32B cachelines; global atomic serialization was ~95% of
// runtime). Workgroups now write partials to d_ws; a second tiny kernel
// reduces. Entropy phase: 16 lanes/block, 8 coeffs/lane, band-packed LDS
// layout (order-invariant reductions), 12 shuffle steps instead of 72.
// -------------------------------------------------------------------------

constexpr double kPi = 3.14159265358979323846;

// constexpr cosine (double): range-reduce + Taylor, applied to the
// float32-rounded argument to match numpy's f32 HARM construction.
constexpr double ccos(double x) {
    while (x > kPi) x -= 2.0 * kPi;
    while (x < -kPi) x += 2.0 * kPi;
    double x2 = x * x;
    double term = 1.0, sum = 1.0;
    for (int k = 1; k <= 24; ++k) {
        term *= -x2 / (double)((2 * k - 1) * (2 * k));
        sum += term;
    }
    return sum;
}

struct DctTables {
    // Indexed [spatial][freq]; normalization folded into freq index.
    float g1[16][16];  // H[j][v] * n_v            (stage 1, row DCT)
    float g2[16][16];  // H[i][u] * n_u * SCALE    (stage 2, col DCT)
    constexpr DctTables() : g1{}, g2{} {
        for (int j = 0; j < 16; ++j) {
            for (int f = 0; f < 16; ++f) {
                float colf = (float)((double)f * kPi) / 32.0f;
                float arg = (2.0f * (float)j + 1.0f) * colf;
                float h = (float)ccos((double)arg);
                float n = (f == 0) ? 0.70710678118654752440f : 1.0f;
                g1[j][f] = h * n;
                g2[j][f] = h * n * 0.17677669529663688110f;  // 1/sqrt(32)
            }
        }
    }
};
constexpr DctTables kT;

#define XS_PITCH 260  // 256 + 4 pad
#define CZ_PITCH 136  // 128 band coeffs + 8 pad (16B-aligned rows)
#define NWG 6144

__global__ __launch_bounds__(256, 4) void dct_entropy_kernel(
    const float* __restrict__ x, float* __restrict__ partials) {
    __shared__ float smem[8336];
    float* Xs = smem;           // 16 x 260 (input strip)
    float* Ts = smem + 4160;    // 16 x 260 (row-DCT, transposed)
    float* Czz = smem;          // 16 x 136 (band-packed coeffs; overlays Xs)
    float* part = smem + 8320;  // 16 per-block entropies

    const int t = threadIdx.x;
    const int g = blockIdx.x;
    const int bc = g >> 8;         // 0..23  (b*c)
    const int br = (g >> 2) & 63;  // block row
    const int cg = g & 3;          // 256-col group
    const float* base =
        x + ((size_t)bc << 20) + ((size_t)br << 14) + ((size_t)cg << 8);

    // ---- global -> LDS: 16 rows x 256 floats, float4, fully coalesced ----
#pragma unroll
    for (int k = 0; k < 4; ++k) {
        int idx = t + 256 * k;  // float4 index within strip
        int row = idx >> 6;
        int c4 = idx & 63;
        float4 ld = *(const float4*)(base + (size_t)row * 1024 + c4 * 4);
        *(float4*)(&Xs[row * XS_PITCH + c4 * 4]) = ld;
    }
    __syncthreads();

    // ---- stage 1: row DCT. thread = (block b, row i) ----
    {
        const int b = t >> 4;
        const int i = t & 15;
        float xr[16];
        const float* src = &Xs[i * XS_PITCH + b * 16];
#pragma unroll
        for (int c = 0; c < 4; ++c) {
            float4 ld = *(const float4*)(src + 4 * c);
            xr[4 * c + 0] = ld.x;
            xr[4 * c + 1] = ld.y;
            xr[4 * c + 2] = ld.z;
            xr[4 * c + 3] = ld.w;
        }
#pragma unroll
        for (int v = 0; v < 16; ++v) {
            float acc = 0.0f;
#pragma unroll
            for (int j = 0; j < 16; ++j) acc = fmaf(xr[j], kT.g1[j][v], acc);
            Ts[v * XS_PITCH + b * 16 + i] = acc;  // transposed write
        }
    }
    __syncthreads();

    // ---- stage 2: col DCT + scale, band-packed write ----
    // Band = {u+v>=16} U {u+v==15, u>=8}. For column v: u >= u_min where
    // u_min = 15-v (v<=7) else 16-v; coeffs packed densely per column at
    // off(v) = v(v+1)/2 (v<=7) else v(v-1)/2+8. Downstream reductions are
    // permutation-invariant, so any dense packing of the band is valid.
    {
        const int b = t >> 4;
        const int v = t & 15;
        float ti[16];
        const float* src = &Ts[v * XS_PITCH + b * 16];
#pragma unroll
        for (int c = 0; c < 4; ++c) {
            float4 ld = *(const float4*)(src + 4 * c);
            ti[4 * c + 0] = ld.x;
            ti[4 * c + 1] = ld.y;
            ti[4 * c + 2] = ld.z;
            ti[4 * c + 3] = ld.w;
        }
        const int hi = (v > 7) ? 1 : 0;
        const int u_min = 15 - v + hi;
        const int off = hi ? (v * (v - 1) / 2 + 8) : (v * (v + 1) / 2);
        float* wbase = &Czz[b * CZ_PITCH + off - u_min];
#pragma unroll
        for (int u = 0; u < 16; ++u) {
            float acc = 0.0f;
#pragma unroll
            for (int i = 0; i < 16; ++i) acc = fmaf(ti[i], kT.g2[i][u], acc);
            if (u >= u_min) wbase[u] = acc;
        }
    }
    __syncthreads();

    // ---- entropy: 16 lanes per block, 8 band coeffs per lane ----
    {
        const int q = t >> 4;  // block 0..15
        const int l = t & 15;
        const float* C = &Czz[q * CZ_PITCH + 8 * l];
        float4 f0 = *(const float4*)C;
        float4 f1 = *(const float4*)(C + 4);
        float c[8] = {f0.x, f0.y, f0.z, f0.w, f1.x, f1.y, f1.z, f1.w};

        float s = ((c[0] + c[1]) + (c[2] + c[3])) +
                  ((c[4] + c[5]) + (c[6] + c[7]));
#pragma unroll
        for (int m = 1; m <= 8; m <<= 1) s += __shfl_xor(s, m);
        const float mean = s * (1.0f / 128.0f);

        float a[8];
        float sq = 0.0f;
#pragma unroll
        for (int j = 0; j < 8; ++j) {
            a[j] = (c[j] < mean) ? 1e-12f : (fabsf(c[j]) + 1e-12f);
            sq = fmaf(a[j], a[j], sq);
        }
#pragma unroll
        for (int m = 1; m <= 8; m <<= 1) sq += __shfl_xor(sq, m);
        const float inv = 1.0f / fmaxf(sqrtf(sq), 1e-12f);

        float e = 0.0f;
#pragma unroll
        for (int j = 0; j < 8; ++j) {
            float p = a[j] * inv;
            e = fmaf(p, __log2f(p), e);
        }
#pragma unroll
        for (int m = 1; m <= 8; m <<= 1) e += __shfl_xor(e, m);
        if (l == 0) part[q] = e;
    }
    __syncthreads();

    if (t == 0) {
        float tot = 0.0f;
#pragma unroll
        for (int i = 0; i < 16; ++i) tot += part[i];
        partials[g] = tot;
    }
}

__global__ __launch_bounds__(256) void reduce_partials(
    const float* __restrict__ partials, float* __restrict__ out) {
    __shared__ float s[4];
    float v = 0.0f;
    for (int i = threadIdx.x; i < NWG; i += 256) v += partials[i];
#pragma unroll
    for (int off = 32; off > 0; off >>= 1) v += __shfl_down(v, off);
    if ((threadIdx.x & 63) == 0) s[threadIdx.x >> 6] = v;
    __syncthreads();
    if (threadIdx.x == 0) {
        float tot = (s[0] + s[1]) + (s[2] + s[3]);
        out[0] = tot * (-1.0f / 98304.0f);
    }
}

extern "C" void kernel_launch(void* const* d_in, const int* in_sizes, int n_in,
                              void* d_out, int out_size, void* d_ws,
                              size_t ws_size, hipStream_t stream) {
    const float* x = (const float*)d_in[0];
    float* out = (float*)d_out;
    float* ws = (float*)d_ws;  // 6144 partial sums
    dct_entropy_kernel<<<NWG, 256, 0, stream>>>(x, ws);
    reduce_partials<<<1, 256, 0, stream>>>(ws, out);
}

// Round 3
// 144.570 us; speedup vs baseline: 2.9694x; 1.0197x over previous
//
#include <hip/hip_runtime.h>
#include <math.h>

// -------------------------------------------------------------------------
// UpperBandEntropyLoss16: 16x16 block DCT -> upper band (128 coeffs)
// -> adaptive threshold -> L2 normalize -> mean entropy (scalar out).
//
// R2 -> R3: wave-autonomous version. Each 64-lane wave owns 4 DCT blocks and
// a private 1 KB LDS region; NO __syncthreads (wave lockstep + in-order LDS
// pipe + s_waitcnt/lgkmcnt clobbers at phase boundaries). Stage 1 reads rows
// directly from global (L1 absorbs the 16B-granular gather), transposes into
// LDS via an XOR-swizzled float4 layout (bank-conflict-free both directions,
// no padding). LDS 34 KB -> 16 KB/wg and VGPR<=64 -> 32 waves/CU (was 16),
// and all barrier drains are gone. Partials -> ws, tiny reduce kernel.
// -------------------------------------------------------------------------

constexpr double kPi = 3.14159265358979323846;

// constexpr cosine (double): range-reduce + Taylor, applied to the
// float32-rounded argument to match numpy's f32 HARM construction.
constexpr double ccos(double x) {
    while (x > kPi) x -= 2.0 * kPi;
    while (x < -kPi) x += 2.0 * kPi;
    double x2 = x * x;
    double term = 1.0, sum = 1.0;
    for (int k = 1; k <= 24; ++k) {
        term *= -x2 / (double)((2 * k - 1) * (2 * k));
        sum += term;
    }
    return sum;
}

struct DctTables {
    // Indexed [spatial][freq]; normalization folded into freq index.
    float g1[16][16];  // H[j][v] * n_v            (stage 1, row DCT)
    float g2[16][16];  // H[i][u] * n_u * SCALE    (stage 2, col DCT)
    constexpr DctTables() : g1{}, g2{} {
        for (int j = 0; j < 16; ++j) {
            for (int f = 0; f < 16; ++f) {
                float colf = (float)((double)f * kPi) / 32.0f;
                float arg = (2.0f * (float)j + 1.0f) * colf;
                float h = (float)ccos((double)arg);
                float n = (f == 0) ? 0.70710678118654752440f : 1.0f;
                g1[j][f] = h * n;
                g2[j][f] = h * n * 0.17677669529663688110f;  // 1/sqrt(32)
            }
        }
    }
};
constexpr DctTables kT;

#define NWG 6144
#define NPART (NWG * 4)

// Intra-wave phase boundary: HW lockstep + in-order LDS pipe give ordering;
// the waitcnt+clobber stops the compiler from hoisting reads over writes.
#define WAVE_LDS_FENCE() asm volatile("s_waitcnt lgkmcnt(0)" ::: "memory")

__global__ __launch_bounds__(256, 8) void dct_entropy_kernel(
    const float* __restrict__ x, float* __restrict__ partials) {
    __shared__ float smem[4096];  // 4 waves x 1024 floats (16 KB)

    const int t = threadIdx.x;
    const int wave = t >> 6;
    const int lane = t & 63;
    const int b = lane >> 4;   // block within wave (0..3)
    const int il = lane & 15;  // stage1: row i; stage2: freq v
    float* R = smem + (wave << 10);

    const int g = blockIdx.x;
    const int bc = g >> 8;         // 0..23  (b*c)
    const int br = (g >> 2) & 63;  // block row
    const int cg = g & 3;          // 256-col group
    const float* base = x + ((size_t)bc << 20) + ((size_t)br << 14) +
                        (cg << 8) + (wave << 6) + (b << 4);

    // ---- stage 1: load row il of block b straight from global ----
    float xr[16];
    {
        const float* gp = base + (size_t)il * 1024;
#pragma unroll
        for (int c = 0; c < 4; ++c) {
            float4 ld = *(const float4*)(gp + 4 * c);
            xr[4 * c + 0] = ld.x;
            xr[4 * c + 1] = ld.y;
            xr[4 * c + 2] = ld.z;
            xr[4 * c + 3] = ld.w;
        }
    }
    // row DCT -> transposed, XOR-swizzled write.
    // Logical slot (row v, col b*16+il); chunk cc = col>>4b... cc = 4b+(il>>2)
    // stored at float4-chunk (cc ^ v) of LDS row v.
    {
        const int cc = (b << 2) + (il >> 2);
        const int lo = il & 3;
#pragma unroll
        for (int v = 0; v < 16; ++v) {
            float acc = 0.0f;
#pragma unroll
            for (int j = 0; j < 16; ++j) acc = fmaf(xr[j], kT.g1[j][v], acc);
            R[(v << 6) + ((cc ^ v) << 2) + lo] = acc;
        }
    }
    WAVE_LDS_FENCE();

    // ---- stage 2: thread (b, v=il) reads 16 cols of LDS row v ----
    float ti[16];
    {
#pragma unroll
        for (int c = 0; c < 4; ++c) {
            const int ch = (b << 2) + c;
            float4 ld = *(const float4*)(&R[(il << 6) + ((ch ^ il) << 2)]);
            ti[4 * c + 0] = ld.x;
            ti[4 * c + 1] = ld.y;
            ti[4 * c + 2] = ld.z;
            ti[4 * c + 3] = ld.w;
        }
    }
    WAVE_LDS_FENCE();
    // col DCT + scale; keep band {u+v>=16} U {u+v==15,u>=8}, packed densely
    // per column at off(v) (order-invariant downstream). Overlays R.
    {
        const int v = il;
        const int hi = (v > 7) ? 1 : 0;
        const int u_min = 15 - v + hi;
        const int off = hi ? (v * (v - 1) / 2 + 8) : (v * (v + 1) / 2);
        float* wb = &R[b * 136 + off - u_min];
#pragma unroll
        for (int u = 0; u < 16; ++u) {
            float acc = 0.0f;
#pragma unroll
            for (int i = 0; i < 16; ++i) acc = fmaf(ti[i], kT.g2[i][u], acc);
            if (u >= u_min) wb[u] = acc;
        }
    }
    WAVE_LDS_FENCE();

    // ---- entropy: 16 lanes per block, 8 band coeffs per lane ----
    {
        const int q = lane >> 4;  // block (== b)
        const float* C = &R[q * 136 + ((lane & 15) << 3)];
        float4 f0 = *(const float4*)C;
        float4 f1 = *(const float4*)(C + 4);
        float c[8] = {f0.x, f0.y, f0.z, f0.w, f1.x, f1.y, f1.z, f1.w};

        float s = ((c[0] + c[1]) + (c[2] + c[3])) +
                  ((c[4] + c[5]) + (c[6] + c[7]));
#pragma unroll
        for (int m = 1; m <= 8; m <<= 1) s += __shfl_xor(s, m);
        const float mean = s * (1.0f / 128.0f);

        float a[8];
        float sq = 0.0f;
#pragma unroll
        for (int j = 0; j < 8; ++j) {
            a[j] = (c[j] < mean) ? 1e-12f : (fabsf(c[j]) + 1e-12f);
            sq = fmaf(a[j], a[j], sq);
        }
#pragma unroll
        for (int m = 1; m <= 8; m <<= 1) sq += __shfl_xor(sq, m);
        const float inv = 1.0f / fmaxf(sqrtf(sq), 1e-12f);

        float e = 0.0f;
#pragma unroll
        for (int j = 0; j < 8; ++j) {
            float p = a[j] * inv;
            e = fmaf(p, __log2f(p), e);
        }
        // within-block reduce (m=1..8), then sum the 4 blocks of this wave
#pragma unroll
        for (int m = 1; m <= 32; m <<= 1) e += __shfl_xor(e, m);
        if (lane == 0) partials[(g << 2) + wave] = e;
    }
}

__global__ __launch_bounds__(1024) void reduce_partials(
    const float* __restrict__ partials, float* __restrict__ out) {
    __shared__ float s[16];
    float v = 0.0f;
    const float4* p4 = (const float4*)partials;
    for (int i = threadIdx.x; i < NPART / 4; i += 1024) {
        float4 f = p4[i];
        v += (f.x + f.y) + (f.z + f.w);
    }
#pragma unroll
    for (int m = 1; m <= 32; m <<= 1) v += __shfl_xor(v, m);
    if ((threadIdx.x & 63) == 0) s[threadIdx.x >> 6] = v;
    __syncthreads();
    if (threadIdx.x < 16) {
        float tot = s[threadIdx.x];
#pragma unroll
        for (int m = 1; m <= 8; m <<= 1) tot += __shfl_xor(tot, m);
        if (threadIdx.x == 0) out[0] = tot * (-1.0f / 98304.0f);
    }
}

extern "C" void kernel_launch(void* const* d_in, const int* in_sizes, int n_in,
                              void* d_out, int out_size, void* d_ws,
                              size_t ws_size, hipStream_t stream) {
    const float* x = (const float*)d_in[0];
    float* out = (float*)d_out;
    float* ws = (float*)d_ws;  // 24576 per-wave partials
    dct_entropy_kernel<<<NWG, 256, 0, stream>>>(x, ws);
    reduce_partials<<<1, 1024, 0, stream>>>(ws, out);
}